// Round 1
// 194.965 us; speedup vs baseline: 1.0116x; 1.0116x over previous
//
#include <hip/hip_runtime.h>

namespace {
constexpr int IW = 512;
constexpr int IH = 512;
constexpr int ID = 64;
constexpr int PS = IH * IW;                      // plane stride (floats)
constexpr float W_Z  = 0.5f;                     // CONTIZ^2
constexpr float W_XY = 2.0f;
constexpr float W_XZ = 1.41421356237309515f;     // 2*CONTIZ = sqrt(2)

constexpr int TPB    = 256;
constexpr int BLOCKS = 1024;    // 2(n) x 2(seg) x 512(h) x 128(chunk) / TPB
constexpr int DSEG   = ID / 2;  // 32 d-steps per segment
}

// packed-fp32 friendly 2-wide vector (v_pk_* on CDNA)
using v2f = __attribute__((ext_vector_type(2))) float;

__device__ __forceinline__ v2f pabs2(v2f t) {
    // |t| = max(t, -t): neg folds into v_pk_max_f32 src modifier
    return __builtin_elementwise_max(t, -t);
}

__global__ __launch_bounds__(TPB) void HessianReg_kernel(const float* __restrict__ img,
                                                         float* __restrict__ out) {
    // XCD swizzle: each XCD owns 128 consecutive logical blocks -> y-neighbor
    // rows stay in the same XCD's L2.
    const int lblk = (blockIdx.x & 7) * (BLOCKS / 8) + (blockIdx.x >> 3);
    const int t     = lblk * TPB + threadIdx.x;
    const int chunk = t & 127;          // float4 index within row
    const int r     = t >> 7;
    const int h     = r & (IH - 1);
    const int q     = r >> 9;           // [0,4)
    const int n     = q & 1;
    const int seg   = q >> 1;
    // d0 is mathematically uniform per block; force SGPR so the z-loop base
    // pointer is scalar (saddr + 32-bit lane voffset addressing, no per-lane
    // 64-bit pointer rolls in the loop).
    const int d0    = __builtin_amdgcn_readfirstlane(seg * DSEG);
    const int w0    = chunk << 2;

    const bool hasW = (chunk < 127);
    const bool hy2  = (h < IH - 1);
    const bool hy3  = (h < IH - 2);

    const float mh = hasW ? 1.f : 0.f;  // mask for x-tail terms (chunk 127)
    const v2f  mv  = {1.f, mh};

    // lane part of the address (floats), excludes d
    const unsigned loff = (unsigned)(n * (ID * PS) + h * IW + w0);
    const float* pz = img + (size_t)d0 * PS;    // uniform, rolled by += PS

    // ---- prologue: rows A=(d0,h), B=(d0,h+1), E=(d0+1,h) -> rolling diffs ----
    float4 A = *(const float4*)(pz + loff);
    float2 a45 = make_float2(0.f, 0.f);
    if (hasW) a45 = *(const float2*)(pz + loff + 4);
    float4 B = make_float4(0.f, 0.f, 0.f, 0.f); float b4 = 0.f;
    if (hy2) { B = *(const float4*)(pz + loff + IW); if (hasW) b4 = (pz + loff)[IW + 4]; }
    float4 E = *(const float4*)(pz + loff + PS);   // d0+1 <= 33 < 64: always valid
    float2 e45 = make_float2(0.f, 0.f);
    if (hasW) e45 = *(const float2*)(pz + loff + PS + 4);

    // x first-differences (5 per row where needed; tail entries garbage->masked)
    v2f   dxA0 = {A.y - A.x, A.z - A.y};
    v2f   dxA1 = {A.w - A.z, a45.x - A.w};
    float dxA4 = a45.y - a45.x;
    v2f   dxB0 = {B.y - B.x, B.z - B.y};
    v2f   dxB1 = {B.w - B.z, b4 - B.w};
    v2f   dxE0 = {E.y - E.x, E.z - E.y};
    v2f   dxE1 = {E.w - E.z, e45.x - E.w};
    float dxE4 = e45.y - e45.x;

    // row values kept for y/z first-differences
    v2f B0v = {B.x, B.y}, B1v = {B.z, B.w};
    v2f E0v = {E.x, E.y}, E1v = {E.z, E.w};
    v2f A0v = {A.x, A.y}, A1v = {A.z, A.w};
    v2f dy10 = B0v - A0v, dy11 = B1v - A1v;   // dy1 = B - A
    v2f dz10 = E0v - A0v, dz11 = E1v - A1v;   // dz1 = E - A

    // weight-separated accumulators (weights applied once at the end)
    float a1s = 0.f;                           // g_xx (scalar, sliding window)
    v2f acc1 = {0.f, 0.f};                     // g_yy            (w=1)
    v2f accz = {0.f, 0.f};                     // g_zz            (w=0.5)
    v2f acc2 = {0.f, 0.f};                     // g_xy            (w=2)
    v2f accs = {0.f, 0.f};                     // g_xz + g_yz     (w=sqrt2)

    #pragma unroll 2
    for (int dl = 0; dl < DSEG; ++dl) {
        const int d = d0 + dl;
        const bool gz2 = (d < ID - 1);  // scalar preds (d uniform)
        const bool gz3 = (d < ID - 2);

        // fresh loads: C=(d,h+2) G=(d+1,h+1) F=(d+2,h) + tails
        float4 C = make_float4(0.f, 0.f, 0.f, 0.f);
        if (hy3) C = *(const float4*)(pz + loff + 2 * IW);
        float4 G = make_float4(0.f, 0.f, 0.f, 0.f); float g4 = 0.f;
        if (gz2 && hy2) { G = *(const float4*)(pz + loff + PS + IW); if (hasW) g4 = (pz + loff)[PS + IW + 4]; }
        float4 F = make_float4(0.f, 0.f, 0.f, 0.f); float2 f45 = make_float2(0.f, 0.f);
        if (gz3) { F = *(const float4*)(pz + loff + 2 * PS); if (hasW) f45 = *(const float2*)(pz + loff + 2 * PS + 4); }

        // ---- stencils from rolled state only (hide load latency) ----
        // g_xx: |dx[w+1]-dx[w]|; last two terms masked on the boundary lane
        {
            float t0 = dxA0.y - dxA0.x;
            float t1 = dxA1.x - dxA0.y;
            float t2 = dxA1.y - dxA1.x;
            float t3 = dxA4   - dxA1.y;
            a1s += fabsf(t0);
            a1s += fabsf(t1);
            a1s  = fmaf(mh, fabsf(t2), a1s);
            a1s  = fmaf(mh, fabsf(t3), a1s);
        }
        if (hy2) {                // g_xy = |dxB - dxA|
            acc2 += pabs2(dxB0 - dxA0);
            acc2 += mv * pabs2(dxB1 - dxA1);      // pk_fma with 0/1 mask
        }
        if (gz2) {                // g_xz = |dxE - dxA|
            accs += pabs2(dxE0 - dxA0);
            accs += mv * pabs2(dxE1 - dxA1);
        }

        // ---- fresh first-differences ----
        v2f   dxF0 = {F.y - F.x, F.z - F.y};
        v2f   dxF1 = {F.w - F.z, f45.x - F.w};
        float dxF4 = f45.y - f45.x;
        v2f   dxG0 = {G.y - G.x, G.z - G.y};
        v2f   dxG1 = {G.w - G.z, g4 - G.w};
        v2f C0v = {C.x, C.y}, C1v = {C.z, C.w};
        v2f G0v = {G.x, G.y}, G1v = {G.z, G.w};
        v2f F0v = {F.x, F.y}, F1v = {F.z, F.w};
        v2f dy20  = C0v - B0v, dy21  = C1v - B1v;   // dy2  = C - B
        v2f dyEG0 = G0v - E0v, dyEG1 = G1v - E1v;   // dyEG = G - E
        v2f dz20  = F0v - E0v, dz21  = F1v - E1v;   // dz2  = F - E

        if (hy3) {                // g_yy = |dy2 - dy1|
            acc1 += pabs2(dy20 - dy10);
            acc1 += pabs2(dy21 - dy11);
        }
        if (gz3) {                // g_zz = |dz2 - dz1|
            accz += pabs2(dz20 - dz10);
            accz += pabs2(dz21 - dz11);
        }
        if (gz2 && hy2) {         // g_yz = |dyEG - dy1|
            accs += pabs2(dyEG0 - dy10);
            accs += pabs2(dyEG1 - dy11);
        }

        // ---- roll z (renamed away by unroll) ----
        dxA0 = dxE0; dxA1 = dxE1; dxA4 = dxE4;
        dxE0 = dxF0; dxE1 = dxF1; dxE4 = dxF4;
        dxB0 = dxG0; dxB1 = dxG1;
        dy10 = dyEG0; dy11 = dyEG1;
        dz10 = dz20;  dz11 = dz21;
        B0v = G0v; B1v = G1v;
        E0v = F0v; E1v = F1v;
        pz += PS;                 // scalar roll (SGPR base)
    }

    float acc = a1s + acc1.x + acc1.y
              + W_Z  * (accz.x + accz.y)
              + W_XY * (acc2.x + acc2.y)
              + W_XZ * (accs.x + accs.y);

    // wave (64-lane) shuffle reduce
    for (int off = 32; off > 0; off >>= 1)
        acc += __shfl_down(acc, off, 64);

    __shared__ float ws[TPB / 64];
    const int lane = threadIdx.x & 63;
    const int wv   = threadIdx.x >> 6;
    if (lane == 0) ws[wv] = acc;
    __syncthreads();
    if (threadIdx.x == 0) {
        float bsum = 0.f;
        #pragma unroll
        for (int i = 0; i < TPB / 64; ++i) bsum += ws[i];
        atomicAdd(out, bsum * (1.0f / (IH * IW)));
    }
}

extern "C" void kernel_launch(void* const* d_in, const int* in_sizes, int n_in,
                              void* d_out, int out_size, void* d_ws, size_t ws_size,
                              hipStream_t stream) {
    const float* img = (const float*)d_in[0];
    float* out = (float*)d_out;
    // d_out is re-poisoned to 0xAA before every timed launch -> zero it on-stream.
    hipMemsetAsync(out, 0, sizeof(float), stream);
    hipLaunchKernelGGL(HessianReg_kernel, dim3(BLOCKS), dim3(TPB), 0, stream, img, out);
}